// Round 8
// baseline (2454.184 us; speedup 1.0000x reference)
//
#include <hip/hip_runtime.h>
#include <cstdint>
#include <cstddef>

#define DEVI __device__ __forceinline__

namespace {

constexpr int Bsz  = 16384;
constexpr int KIN  = 256;
constexpr int KST  = 1024;
constexpr int KOUT = 256;

typedef __bf16 bf16x8 __attribute__((ext_vector_type(8)));
typedef float  f32x4  __attribute__((ext_vector_type(4)));

DEVI float sigmoidf_(float x) { return 1.0f / (1.0f + expf(-x)); }

DEVI void gload16(const void* gsrc, void* ldst) {
    // async global->LDS, 16B per lane; LDS dest = wave-uniform base + lane*16
    __builtin_amdgcn_global_load_lds((__attribute__((address_space(1))) void*)gsrc,
                                     (__attribute__((address_space(3))) void*)ldst,
                                     16, 0, 0);
}

// ---------------- epilogues (r,c local to the chunk) ----------------
struct EpX0 {                  // x0 = tanh(v + b_in[c]) -> bf16
    __bf16* out; const float* bias;
    DEVI void begin() {}
    DEVI void store(float v, int r, int c) { out[(size_t)r * KST + c] = (__bf16)tanhf(v + bias[c]); }
};
struct EpLx {                  // lx = v -> bf16 (ldo = 3K)
    __bf16* out;
    DEVI void begin() {}
    DEVI void store(float v, int r, int c) { out[(size_t)r * (3 * KST) + c] = (__bf16)v; }
};
template <class HT>
struct EpGates {               // g = sigmoid(lx + v + b_hg); Z(bf16) or RH = bf16(g*h)
    __bf16* Z; __bf16* RH; const __bf16* lx; const float* bhg; const HT* h;
    DEVI void begin() {}
    DEVI void store(float v, int r, int c) {
        const float g = sigmoidf_((float)lx[(size_t)r * (3 * KST) + c] + v + bhg[c]);
        if (c < KST) {
            Z[(size_t)r * KST + c] = (__bf16)g;
        } else {
            const size_t i = (size_t)r * KST + (c - KST);
            RH[i] = (__bf16)(g * (float)h[i]);
        }
    }
};
// lin = lx[.,2K+c] + v + b_hl; k = Z*(tanh(lin)-h); RK4 update (MEANDT==1).
// STAGE 0..2: acc(f32) accumulates k-combo, hn(bf16) = next h.
// STAGE 3: acc = state + dt*(acc+k)/6 (final state_new, f32) and hn = bf16 copy of it.
template <int STAGE, class HT>
struct EpLin {
    const __bf16* Z; const __bf16* lx; const float* bhl; const HT* h;
    const float* state; float* acc; __bf16* hn; const float* dtp;
    float dtv;
    DEVI void begin() { dtv = *dtp; }
    DEVI void store(float v, int r, int c) {
        const size_t i = (size_t)r * KST + c;
        const float lin = (float)lx[(size_t)r * (3 * KST) + 2 * KST + c] + v + bhl[c];
        const float k = (float)Z[i] * (tanhf(lin) - (float)h[i]);
        if constexpr (STAGE == 0)      { acc[i] = k;            hn[i] = (__bf16)(state[i] + 0.5f * dtv * k); }
        else if constexpr (STAGE == 1) { acc[i] += 2.f * k;     hn[i] = (__bf16)(state[i] + 0.5f * dtv * k); }
        else if constexpr (STAGE == 2) { acc[i] += 2.f * k;     hn[i] = (__bf16)(state[i] + dtv * k); }
        else { const float s = state[i] + dtv * (acc[i] + k) * (1.f / 6.f); acc[i] = s; hn[i] = (__bf16)s; }
    }
};
struct EpT {                   // y1 = tanh(v) -> bf16
    __bf16* out;
    DEVI void begin() {}
    DEVI void store(float v, int r, int c) { out[(size_t)r * KST + c] = (__bf16)tanhf(v); }
};
struct EpY {                   // y = v (fp32 final output)
    float* out;
    DEVI void begin() {}
    DEVI void store(float v, int r, int c) { out[(size_t)r * KOUT + c] = v; }
};

// ---------------- bf16 MFMA NT GEMM (m97 structure) ----------------
// C[M,N] = A[M,K] @ W[N,K]^T. 128x128 tile, BK=32, 4 waves (2x2 of 64x64),
// 16x16x32 MFMA, 4x4 frags/wave, global_load_lds width 16, linear LDS,
// 2 barriers per K-step.
template <class Ep>
__global__ __launch_bounds__(256)
void gemm_bt(const __bf16* __restrict__ A, const __bf16* __restrict__ W,
             const int K, Ep ep)
{
    __shared__ __bf16 As[128 * 32];
    __shared__ __bf16 Bs[128 * 32];
    const int m0 = blockIdx.x * 128;
    const int n0 = blockIdx.y * 128;
    const int t  = threadIdx.x;
    const int l  = t & 63;
    const int w  = t >> 6;          // wave 0..3
    const int wr = w >> 1;          // wave row (0..1) -> 64 rows
    const int wc = w & 1;           // wave col (0..1) -> 64 cols
    const int fr = l & 15;          // fragment row/col index
    const int fq = l >> 4;          // k-quad 0..3 (8 bf16 each)
    const int srow = t >> 2;        // staging row 0..63
    const int sk   = (t & 3) << 3;  // staging k elem 0,8,16,24

    const __bf16* Ap0 = A + (size_t)(m0 + srow) * K + sk;
    const __bf16* Ap1 = Ap0 + (size_t)64 * K;
    const __bf16* Bp0 = W + (size_t)(n0 + srow) * K + sk;
    const __bf16* Bp1 = Bp0 + (size_t)64 * K;
    __bf16* la0 = &As[t * 8];
    __bf16* la1 = &As[2048 + t * 8];
    __bf16* lb0 = &Bs[t * 8];
    __bf16* lb1 = &Bs[2048 + t * 8];

    f32x4 acc[4][4];
#pragma unroll
    for (int i = 0; i < 4; ++i)
#pragma unroll
        for (int j = 0; j < 4; ++j) acc[i][j] = (f32x4){0.f, 0.f, 0.f, 0.f};

    for (int k0 = 0; k0 < K; k0 += 32) {
        gload16(Ap0 + k0, la0);
        gload16(Ap1 + k0, la1);
        gload16(Bp0 + k0, lb0);
        gload16(Bp1 + k0, lb1);
        __syncthreads();            // drains vmcnt -> LDS tile ready
        bf16x8 av[4], bv[4];
#pragma unroll
        for (int mi = 0; mi < 4; ++mi)
            av[mi] = *(const bf16x8*)&As[(wr * 64 + mi * 16 + fr) * 32 + fq * 8];
#pragma unroll
        for (int ni = 0; ni < 4; ++ni)
            bv[ni] = *(const bf16x8*)&Bs[(wc * 64 + ni * 16 + fr) * 32 + fq * 8];
#pragma unroll
        for (int mi = 0; mi < 4; ++mi)
#pragma unroll
            for (int ni = 0; ni < 4; ++ni)
                acc[mi][ni] = __builtin_amdgcn_mfma_f32_16x16x32_bf16(av[mi], bv[ni], acc[mi][ni], 0, 0, 0);
        __syncthreads();            // compute done before next tile overwrite
    }

    ep.begin();
#pragma unroll
    for (int mi = 0; mi < 4; ++mi)
#pragma unroll
        for (int ni = 0; ni < 4; ++ni)
#pragma unroll
            for (int j = 0; j < 4; ++j)
                ep.store(acc[mi][ni][j],
                         m0 + wr * 64 + mi * 16 + fq * 4 + j,
                         n0 + wc * 64 + ni * 16 + fr);
}

// ---------------- f32 -> bf16 conversion (vectorized, grid-stride) ----------------
__global__ __launch_bounds__(256)
void cvt_bf16(const float* __restrict__ s, __bf16* __restrict__ d, int n8)
{
    for (int i = blockIdx.x * blockDim.x + threadIdx.x; i < n8; i += gridDim.x * blockDim.x) {
        const float4 a = ((const float4*)s)[2 * i];
        const float4 b = ((const float4*)s)[2 * i + 1];
        bf16x8 v;
        v[0] = (__bf16)a.x; v[1] = (__bf16)a.y; v[2] = (__bf16)a.z; v[3] = (__bf16)a.w;
        v[4] = (__bf16)b.x; v[5] = (__bf16)b.y; v[6] = (__bf16)b.z; v[7] = (__bf16)b.w;
        ((bf16x8*)d)[i] = v;
    }
}

} // namespace

extern "C" void kernel_launch(void* const* d_in, const int* in_sizes, int n_in,
                              void* d_out, int out_size, void* d_ws, size_t ws_size,
                              hipStream_t stream)
{
    (void)in_sizes; (void)n_in; (void)out_size;

    const float* x     = (const float*)d_in[0];
    const float* state = (const float*)d_in[1];
    const float* dtp   = (const float*)d_in[2];
    const float* W_in  = (const float*)d_in[3];
    const float* b_in  = (const float*)d_in[4];
    const float* W_lx  = (const float*)d_in[5];
    const float* W_hg  = (const float*)d_in[6];
    const float* b_hg  = (const float*)d_in[7];
    const float* W_hl  = (const float*)d_in[8];
    const float* b_hl  = (const float*)d_in[9];
    const float* W_y1  = (const float*)d_in[10];
    const float* W_y2  = (const float*)d_in[11];

    float* y_out  = (float*)d_out;                    // [B, KOUT] f32
    float* st_new = y_out + (size_t)Bsz * KOUT;       // [B, KST] f32; doubles as RK4 acc

    // ---- workspace layout ----
    // fixed: x_bf | state_bf | stn_bf | 6 bf16 weight buffers  (~88 MB)
    // chunk (all bf16 now): lx (6 CB*K B) | Z (2) | h_bf (2) | RH (2) = 12*CB*K bytes
    // CB=16384 (no chunk loop) needs ~289 MB total; CB=8192 needs ~188 MB.
    const size_t nWin = (size_t)KST * KIN, nWlx = (size_t)3 * KST * KST,
                 nWhg = (size_t)2 * KST * KST, nWhl = (size_t)KST * KST,
                 nWy1 = (size_t)KST * KST, nWy2 = (size_t)KOUT * KST;
    const size_t fixedB = ((size_t)Bsz * KIN + 2 * (size_t)Bsz * KST
                           + nWin + nWlx + nWhg + nWhl + nWy1 + nWy2) * 2;

    int CB = 1024;
    while (CB < Bsz && fixedB + (size_t)(2 * CB) * KST * 12 <= ws_size) CB <<= 1;
    if (fixedB + (size_t)CB * KST * 12 > ws_size) return;

    uint8_t* p = (uint8_t*)d_ws;
    __bf16* x_bf  = (__bf16*)p; p += (size_t)Bsz * KIN * 2;
    __bf16* st_bf = (__bf16*)p; p += (size_t)Bsz * KST * 2;
    __bf16* snb   = (__bf16*)p; p += (size_t)Bsz * KST * 2;
    __bf16* Wb_in = (__bf16*)p; p += nWin * 2;
    __bf16* Wb_lx = (__bf16*)p; p += nWlx * 2;
    __bf16* Wb_hg = (__bf16*)p; p += nWhg * 2;
    __bf16* Wb_hl = (__bf16*)p; p += nWhl * 2;
    __bf16* Wb_y1 = (__bf16*)p; p += nWy1 * 2;
    __bf16* Wb_y2 = (__bf16*)p; p += nWy2 * 2;
    __bf16* lx    = (__bf16*)p; p += (size_t)CB * 3 * KST * 2;   // bf16 now
    __bf16* Zb    = (__bf16*)p; p += (size_t)CB * KST * 2;       // bf16 now
    __bf16* h_bf  = (__bf16*)p; p += (size_t)CB * KST * 2;
    __bf16* RH    = (__bf16*)p;
    // y-phase scratch aliases lx+Zb (both dead by then): needs 4*CB*K*2 = 8*CB*K
    // bytes; lx(6*CB*K) + Zb(2*CB*K) = exactly 8*CB*K, contiguous.
    __bf16* t_bf  = lx;

    const dim3 blk(256);
    auto cg = [](size_t n) { return dim3((unsigned)((n / 8 + 255) / 256 > 2048 ? 2048 : (n / 8 + 255) / 256)); };
    auto g  = [](int M, int N) { return dim3((unsigned)(M / 128), (unsigned)(N / 128)); };

    // ---- one-time f32 -> bf16 conversions ----
    cvt_bf16<<<cg((size_t)Bsz * KIN), blk, 0, stream>>>(x, x_bf, (int)((size_t)Bsz * KIN / 8));
    cvt_bf16<<<cg((size_t)Bsz * KST), blk, 0, stream>>>(state, st_bf, (int)((size_t)Bsz * KST / 8));
    cvt_bf16<<<cg(nWin), blk, 0, stream>>>(W_in, Wb_in, (int)(nWin / 8));
    cvt_bf16<<<cg(nWlx), blk, 0, stream>>>(W_lx, Wb_lx, (int)(nWlx / 8));
    cvt_bf16<<<cg(nWhg), blk, 0, stream>>>(W_hg, Wb_hg, (int)(nWhg / 8));
    cvt_bf16<<<cg(nWhl), blk, 0, stream>>>(W_hl, Wb_hl, (int)(nWhl / 8));
    cvt_bf16<<<cg(nWy1), blk, 0, stream>>>(W_y1, Wb_y1, (int)(nWy1 / 8));
    cvt_bf16<<<cg(nWy2), blk, 0, stream>>>(W_y2, Wb_y2, (int)(nWy2 / 8));

    for (int c0 = 0; c0 < Bsz; c0 += CB) {
        const __bf16* xs  = x_bf + (size_t)c0 * KIN;
        const __bf16* ssb = st_bf + (size_t)c0 * KST;
        const float*  ss  = state + (size_t)c0 * KST;
        float*  sn   = st_new + (size_t)c0 * KST;
        __bf16* snbs = snb + (size_t)c0 * KST;

        // x0 = tanh(x W_in^T + b_in)  [bf16 -> h_bf]
        gemm_bt<<<g(CB, KST), blk, 0, stream>>>(xs, Wb_in, KIN, EpX0{h_bf, b_in});
        // lx = x0 W_lx^T  [bf16]
        gemm_bt<<<g(CB, 3 * KST), blk, 0, stream>>>(h_bf, Wb_lx, KST, EpLx{lx});

        // RK4 stage 0 (h = state)
        gemm_bt<<<g(CB, 2 * KST), blk, 0, stream>>>(ssb, Wb_hg, KST, EpGates<float>{Zb, RH, lx, b_hg, ss});
        gemm_bt<<<g(CB, KST), blk, 0, stream>>>(RH, Wb_hl, KST, EpLin<0, float>{Zb, lx, b_hl, ss, ss, sn, h_bf, dtp});
        // stages 1..3 (h = h_bf)
        gemm_bt<<<g(CB, 2 * KST), blk, 0, stream>>>(h_bf, Wb_hg, KST, EpGates<__bf16>{Zb, RH, lx, b_hg, h_bf});
        gemm_bt<<<g(CB, KST), blk, 0, stream>>>(RH, Wb_hl, KST, EpLin<1, __bf16>{Zb, lx, b_hl, h_bf, ss, sn, h_bf, dtp});
        gemm_bt<<<g(CB, 2 * KST), blk, 0, stream>>>(h_bf, Wb_hg, KST, EpGates<__bf16>{Zb, RH, lx, b_hg, h_bf});
        gemm_bt<<<g(CB, KST), blk, 0, stream>>>(RH, Wb_hl, KST, EpLin<2, __bf16>{Zb, lx, b_hl, h_bf, ss, sn, h_bf, dtp});
        gemm_bt<<<g(CB, 2 * KST), blk, 0, stream>>>(h_bf, Wb_hg, KST, EpGates<__bf16>{Zb, RH, lx, b_hg, h_bf});
        gemm_bt<<<g(CB, KST), blk, 0, stream>>>(RH, Wb_hl, KST, EpLin<3, __bf16>{Zb, lx, b_hl, h_bf, ss, sn, snbs, dtp});
    }

    // y = tanh(state_new W_y1^T) W_y2^T ; t_bf reuses lx+Zb region
    const int CBY = (4 * CB < Bsz) ? 4 * CB : Bsz;
    for (int c0 = 0; c0 < Bsz; c0 += CBY) {
        gemm_bt<<<g(CBY, KST), blk, 0, stream>>>(snb + (size_t)c0 * KST, Wb_y1, KST, EpT{t_bf});
        gemm_bt<<<g(CBY, KOUT), blk, 0, stream>>>(t_bf, Wb_y2, KST, EpY{y_out + (size_t)c0 * KOUT});
    }
}

// Round 9
// 1539.273 us; speedup vs baseline: 1.5944x; 1.5944x over previous
//
#include <hip/hip_runtime.h>
#include <cstdint>
#include <cstddef>

#define DEVI __device__ __forceinline__

namespace {

constexpr int Bsz  = 16384;
constexpr int KIN  = 256;
constexpr int KST  = 1024;
constexpr int KOUT = 256;

typedef __bf16 bf16x8 __attribute__((ext_vector_type(8)));
typedef float  f32x4  __attribute__((ext_vector_type(4)));

DEVI float sigmoidf_(float x) { return 1.0f / (1.0f + expf(-x)); }

DEVI void gload16(const void* gsrc, void* ldst) {
    __builtin_amdgcn_global_load_lds((__attribute__((address_space(1))) void*)gsrc,
                                     (__attribute__((address_space(3))) void*)ldst,
                                     16, 0, 0);
}

// ---- vectorized 8-element load/store helpers (all 16B-aligned by layout) ----
DEVI void ld8f(const float* p, float* v) {
    const float4 a = *(const float4*)p;
    const float4 b = *(const float4*)(p + 4);
    v[0]=a.x; v[1]=a.y; v[2]=a.z; v[3]=a.w;
    v[4]=b.x; v[5]=b.y; v[6]=b.z; v[7]=b.w;
}
DEVI void st8f(float* p, const float* v) {
    *(float4*)p       = (float4){v[0],v[1],v[2],v[3]};
    *(float4*)(p + 4) = (float4){v[4],v[5],v[6],v[7]};
}
DEVI void ld8bf(const __bf16* p, float* v) {
    const bf16x8 o = *(const bf16x8*)p;
#pragma unroll
    for (int i = 0; i < 8; ++i) v[i] = (float)o[i];
}
DEVI void st8bf(__bf16* p, const float* v) {
    bf16x8 o;
#pragma unroll
    for (int i = 0; i < 8; ++i) o[i] = (__bf16)v[i];
    *(bf16x8*)p = o;
}
DEVI void ld8h(const float* p, float* v)  { ld8f(p, v); }
DEVI void ld8h(const __bf16* p, float* v) { ld8bf(p, v); }

// ---------------- epilogues: store16(v[16], row, col0), col0 % 16 == 0 ----------------
struct EpX0 {                  // x0 = tanh(v + b_in[c]) -> bf16
    __bf16* out; const float* bias;
    DEVI void begin() {}
    DEVI void store16(const float* v, int r, int c) {
#pragma unroll
        for (int q = 0; q < 2; ++q) {
            float b[8], o[8];
            ld8f(bias + c + q * 8, b);
#pragma unroll
            for (int e = 0; e < 8; ++e) o[e] = tanhf(v[q*8+e] + b[e]);
            st8bf(out + (size_t)r * KST + c + q * 8, o);
        }
    }
};
struct EpLx {                  // lx = v -> bf16 (ldo = 3K)
    __bf16* out;
    DEVI void begin() {}
    DEVI void store16(const float* v, int r, int c) {
#pragma unroll
        for (int q = 0; q < 2; ++q)
            st8bf(out + (size_t)r * (3 * KST) + c + q * 8, v + q * 8);
    }
};
template <class HT>
struct EpGates {               // g = sigmoid(lx + v + b_hg); Z(bf16) or RH = bf16(g*h)
    __bf16* Z; __bf16* RH; const __bf16* lx; const float* bhg; const HT* h;
    DEVI void begin() {}
    DEVI void store16(const float* v, int r, int c) {
#pragma unroll
        for (int q = 0; q < 2; ++q) {
            float l[8], b[8], g[8];
            ld8bf(lx + (size_t)r * (3 * KST) + c + q * 8, l);
            ld8f(bhg + c + q * 8, b);
#pragma unroll
            for (int e = 0; e < 8; ++e) g[e] = sigmoidf_(l[e] + v[q*8+e] + b[e]);
            if (c < KST) {     // uniform per block: n0 multiple of 128 divides K boundary
                st8bf(Z + (size_t)r * KST + c + q * 8, g);
            } else {
                const size_t i = (size_t)r * KST + (c - KST) + q * 8;
                float hh[8];
                ld8h(h + i, hh);
#pragma unroll
                for (int e = 0; e < 8; ++e) g[e] *= hh[e];
                st8bf(RH + i, g);
            }
        }
    }
};
// lin = lx[.,2K+c] + v + b_hl; k = Z*(tanh(lin)-h); RK4 update (MEANDT==1).
template <int STAGE, class HT>
struct EpLin {
    const __bf16* Z; const __bf16* lx; const float* bhl; const HT* h;
    const float* state; float* acc; __bf16* hn; const float* dtp;
    float dtv;
    DEVI void begin() { dtv = *dtp; }
    DEVI void store16(const float* v, int r, int c) {
#pragma unroll
        for (int q = 0; q < 2; ++q) {
            const size_t i = (size_t)r * KST + c + q * 8;
            float l[8], z[8], hh[8], st[8], b[8], kk[8], ov[8], hv[8];
            ld8bf(lx + (size_t)r * (3 * KST) + 2 * KST + c + q * 8, l);
            ld8bf(Z + i, z);
            ld8h(h + i, hh);
            ld8f(state + i, st);
            ld8f(bhl + c + q * 8, b);
#pragma unroll
            for (int e = 0; e < 8; ++e)
                kk[e] = z[e] * (tanhf(l[e] + v[q*8+e] + b[e]) - hh[e]);
            if constexpr (STAGE == 0) {
#pragma unroll
                for (int e = 0; e < 8; ++e) { ov[e] = kk[e]; hv[e] = st[e] + 0.5f * dtv * kk[e]; }
            } else if constexpr (STAGE == 1 || STAGE == 2) {
                float a[8]; ld8f(acc + i, a);
                const float hc = (STAGE == 1) ? 0.5f : 1.0f;
#pragma unroll
                for (int e = 0; e < 8; ++e) { ov[e] = a[e] + 2.f * kk[e]; hv[e] = st[e] + hc * dtv * kk[e]; }
            } else {
                float a[8]; ld8f(acc + i, a);
#pragma unroll
                for (int e = 0; e < 8; ++e) { ov[e] = st[e] + dtv * (a[e] + kk[e]) * (1.f / 6.f); hv[e] = ov[e]; }
            }
            st8f(acc + i, ov);
            st8bf(hn + i, hv);
        }
    }
};
struct EpT {                   // y1 = tanh(v) -> bf16
    __bf16* out;
    DEVI void begin() {}
    DEVI void store16(const float* v, int r, int c) {
#pragma unroll
        for (int q = 0; q < 2; ++q) {
            float o[8];
#pragma unroll
            for (int e = 0; e < 8; ++e) o[e] = tanhf(v[q*8+e]);
            st8bf(out + (size_t)r * KST + c + q * 8, o);
        }
    }
};
struct EpY {                   // y = v (fp32 final output)
    float* out;
    DEVI void begin() {}
    DEVI void store16(const float* v, int r, int c) {
        st8f(out + (size_t)r * KOUT + c, v);
        st8f(out + (size_t)r * KOUT + c + 8, v + 8);
    }
};

// ---------------- bf16 MFMA NT GEMM (m97 structure + LDS-bounce epilogue) ----------------
// C[M,N] = A[M,K] @ W[N,K]^T. 128x128 tile, BK=32, 4 waves (2x2 of 64x64),
// 16x16x32 MFMA, global_load_lds width 16, linear LDS, 2 barriers per K-step.
// Epilogue: acc -> LDS bounce (4 bands x 32 rows, stride 132) -> each thread
// owns 16 consecutive cols of one row -> fully vectorized/coalesced global I/O.
template <class Ep>
__global__ __launch_bounds__(256)
void gemm_bt(const __bf16* __restrict__ A, const __bf16* __restrict__ W,
             const int K, Ep ep)
{
    __shared__ __bf16 As[128 * 32];
    __shared__ __bf16 Bs[128 * 32];
    __shared__ float  bounce[32 * 132];
    const int m0 = blockIdx.x * 128;
    const int n0 = blockIdx.y * 128;
    const int t  = threadIdx.x;
    const int l  = t & 63;
    const int w  = t >> 6;          // wave 0..3
    const int wr = w >> 1;          // wave row (0..1) -> 64 rows
    const int wc = w & 1;           // wave col (0..1) -> 64 cols
    const int fr = l & 15;          // fragment row/col index
    const int fq = l >> 4;          // k-quad 0..3
    const int srow = t >> 2;        // staging row 0..63
    const int sk   = (t & 3) << 3;  // staging k elem 0,8,16,24

    const __bf16* Ap0 = A + (size_t)(m0 + srow) * K + sk;
    const __bf16* Ap1 = Ap0 + (size_t)64 * K;
    const __bf16* Bp0 = W + (size_t)(n0 + srow) * K + sk;
    const __bf16* Bp1 = Bp0 + (size_t)64 * K;
    __bf16* la0 = &As[t * 8];
    __bf16* la1 = &As[2048 + t * 8];
    __bf16* lb0 = &Bs[t * 8];
    __bf16* lb1 = &Bs[2048 + t * 8];

    f32x4 acc[4][4];
#pragma unroll
    for (int i = 0; i < 4; ++i)
#pragma unroll
        for (int j = 0; j < 4; ++j) acc[i][j] = (f32x4){0.f, 0.f, 0.f, 0.f};

    for (int k0 = 0; k0 < K; k0 += 32) {
        gload16(Ap0 + k0, la0);
        gload16(Ap1 + k0, la1);
        gload16(Bp0 + k0, lb0);
        gload16(Bp1 + k0, lb1);
        __syncthreads();
        bf16x8 av[4], bv[4];
#pragma unroll
        for (int mi = 0; mi < 4; ++mi)
            av[mi] = *(const bf16x8*)&As[(wr * 64 + mi * 16 + fr) * 32 + fq * 8];
#pragma unroll
        for (int ni = 0; ni < 4; ++ni)
            bv[ni] = *(const bf16x8*)&Bs[(wc * 64 + ni * 16 + fr) * 32 + fq * 8];
#pragma unroll
        for (int mi = 0; mi < 4; ++mi)
#pragma unroll
            for (int ni = 0; ni < 4; ++ni)
                acc[mi][ni] = __builtin_amdgcn_mfma_f32_16x16x32_bf16(av[mi], bv[ni], acc[mi][ni], 0, 0, 0);
        __syncthreads();
    }

    // ---- LDS-bounce epilogue: band = 32 rows. Old mapping row = wr*64+mi*16+fq*4+j,
    // so band b holds wr = b>>1, mi in {2(b&1), 2(b&1)+1}. Stride 132: write-phase
    // banks are exactly 2-way (free); read phase is 16B-vector loads. ----
    ep.begin();
#pragma unroll
    for (int band = 0; band < 4; ++band) {
        if (wr == (band >> 1)) {
            const int mi0 = 2 * (band & 1);
#pragma unroll
            for (int mm = 0; mm < 2; ++mm)
#pragma unroll
                for (int ni = 0; ni < 4; ++ni)
#pragma unroll
                    for (int j = 0; j < 4; ++j)
                        bounce[(mm * 16 + fq * 4 + j) * 132 + wc * 64 + ni * 16 + fr]
                            = acc[mi0 + mm][ni][j];
        }
        __syncthreads();
        {
            const int r  = t >> 3;          // 0..31
            const int c0 = (t & 7) * 16;    // 0..112
            float v[16];
#pragma unroll
            for (int kk = 0; kk < 16; ++kk) v[kk] = bounce[r * 132 + c0 + kk];
            ep.store16(v, m0 + band * 32 + r, n0 + c0);
        }
        __syncthreads();
    }
}

// ---------------- f32 -> bf16 conversion (vectorized, grid-stride) ----------------
__global__ __launch_bounds__(256)
void cvt_bf16(const float* __restrict__ s, __bf16* __restrict__ d, int n8)
{
    for (int i = blockIdx.x * blockDim.x + threadIdx.x; i < n8; i += gridDim.x * blockDim.x) {
        const float4 a = ((const float4*)s)[2 * i];
        const float4 b = ((const float4*)s)[2 * i + 1];
        bf16x8 v;
        v[0] = (__bf16)a.x; v[1] = (__bf16)a.y; v[2] = (__bf16)a.z; v[3] = (__bf16)a.w;
        v[4] = (__bf16)b.x; v[5] = (__bf16)b.y; v[6] = (__bf16)b.z; v[7] = (__bf16)b.w;
        ((bf16x8*)d)[i] = v;
    }
}

} // namespace

extern "C" void kernel_launch(void* const* d_in, const int* in_sizes, int n_in,
                              void* d_out, int out_size, void* d_ws, size_t ws_size,
                              hipStream_t stream)
{
    (void)in_sizes; (void)n_in; (void)out_size;

    const float* x     = (const float*)d_in[0];
    const float* state = (const float*)d_in[1];
    const float* dtp   = (const float*)d_in[2];
    const float* W_in  = (const float*)d_in[3];
    const float* b_in  = (const float*)d_in[4];
    const float* W_lx  = (const float*)d_in[5];
    const float* W_hg  = (const float*)d_in[6];
    const float* b_hg  = (const float*)d_in[7];
    const float* W_hl  = (const float*)d_in[8];
    const float* b_hl  = (const float*)d_in[9];
    const float* W_y1  = (const float*)d_in[10];
    const float* W_y2  = (const float*)d_in[11];

    float* y_out  = (float*)d_out;                    // [B, KOUT] f32
    float* st_new = y_out + (size_t)Bsz * KOUT;       // [B, KST] f32; doubles as RK4 acc

    // ---- workspace layout ----
    // fixed: x_bf | state_bf | stn_bf | 6 bf16 weight buffers  (~88 MB)
    // chunk (bf16): lx (6 CB*K B) | Z (2) | h_bf (2) | RH (2) = 12*CB*K bytes
    // CB capped at 8192: keeps per-dispatch streaming footprint inside L3
    // (CB=16384 thrashed A-operand re-reads -> round 8 regression).
    const size_t nWin = (size_t)KST * KIN, nWlx = (size_t)3 * KST * KST,
                 nWhg = (size_t)2 * KST * KST, nWhl = (size_t)KST * KST,
                 nWy1 = (size_t)KST * KST, nWy2 = (size_t)KOUT * KST;
    const size_t fixedB = ((size_t)Bsz * KIN + 2 * (size_t)Bsz * KST
                           + nWin + nWlx + nWhg + nWhl + nWy1 + nWy2) * 2;

    int CB = 1024;
    while (CB < 8192 && fixedB + (size_t)(2 * CB) * KST * 12 <= ws_size) CB <<= 1;
    if (fixedB + (size_t)CB * KST * 12 > ws_size) return;

    uint8_t* p = (uint8_t*)d_ws;
    __bf16* x_bf  = (__bf16*)p; p += (size_t)Bsz * KIN * 2;
    __bf16* st_bf = (__bf16*)p; p += (size_t)Bsz * KST * 2;
    __bf16* snb   = (__bf16*)p; p += (size_t)Bsz * KST * 2;
    __bf16* Wb_in = (__bf16*)p; p += nWin * 2;
    __bf16* Wb_lx = (__bf16*)p; p += nWlx * 2;
    __bf16* Wb_hg = (__bf16*)p; p += nWhg * 2;
    __bf16* Wb_hl = (__bf16*)p; p += nWhl * 2;
    __bf16* Wb_y1 = (__bf16*)p; p += nWy1 * 2;
    __bf16* Wb_y2 = (__bf16*)p; p += nWy2 * 2;
    __bf16* lx    = (__bf16*)p; p += (size_t)CB * 3 * KST * 2;
    __bf16* Zb    = (__bf16*)p; p += (size_t)CB * KST * 2;
    __bf16* h_bf  = (__bf16*)p; p += (size_t)CB * KST * 2;
    __bf16* RH    = (__bf16*)p;
    // y-phase scratch aliases lx+Zb (dead by then): needs CBY*K*2 <= 8*CB*K bytes.
    __bf16* t_bf  = lx;

    const dim3 blk(256);
    auto cg = [](size_t n) { return dim3((unsigned)((n / 8 + 255) / 256 > 2048 ? 2048 : (n / 8 + 255) / 256)); };
    auto g  = [](int M, int N) { return dim3((unsigned)(M / 128), (unsigned)(N / 128)); };

    // ---- one-time f32 -> bf16 conversions ----
    cvt_bf16<<<cg((size_t)Bsz * KIN), blk, 0, stream>>>(x, x_bf, (int)((size_t)Bsz * KIN / 8));
    cvt_bf16<<<cg((size_t)Bsz * KST), blk, 0, stream>>>(state, st_bf, (int)((size_t)Bsz * KST / 8));
    cvt_bf16<<<cg(nWin), blk, 0, stream>>>(W_in, Wb_in, (int)(nWin / 8));
    cvt_bf16<<<cg(nWlx), blk, 0, stream>>>(W_lx, Wb_lx, (int)(nWlx / 8));
    cvt_bf16<<<cg(nWhg), blk, 0, stream>>>(W_hg, Wb_hg, (int)(nWhg / 8));
    cvt_bf16<<<cg(nWhl), blk, 0, stream>>>(W_hl, Wb_hl, (int)(nWhl / 8));
    cvt_bf16<<<cg(nWy1), blk, 0, stream>>>(W_y1, Wb_y1, (int)(nWy1 / 8));
    cvt_bf16<<<cg(nWy2), blk, 0, stream>>>(W_y2, Wb_y2, (int)(nWy2 / 8));

    for (int c0 = 0; c0 < Bsz; c0 += CB) {
        const __bf16* xs  = x_bf + (size_t)c0 * KIN;
        const __bf16* ssb = st_bf + (size_t)c0 * KST;
        const float*  ss  = state + (size_t)c0 * KST;
        float*  sn   = st_new + (size_t)c0 * KST;
        __bf16* snbs = snb + (size_t)c0 * KST;

        // x0 = tanh(x W_in^T + b_in)  [bf16 -> h_bf]
        gemm_bt<<<g(CB, KST), blk, 0, stream>>>(xs, Wb_in, KIN, EpX0{h_bf, b_in});
        // lx = x0 W_lx^T  [bf16]
        gemm_bt<<<g(CB, 3 * KST), blk, 0, stream>>>(h_bf, Wb_lx, KST, EpLx{lx});

        // RK4 stage 0 (h = state)
        gemm_bt<<<g(CB, 2 * KST), blk, 0, stream>>>(ssb, Wb_hg, KST, EpGates<float>{Zb, RH, lx, b_hg, ss});
        gemm_bt<<<g(CB, KST), blk, 0, stream>>>(RH, Wb_hl, KST, EpLin<0, float>{Zb, lx, b_hl, ss, ss, sn, h_bf, dtp});
        // stages 1..3 (h = h_bf)
        gemm_bt<<<g(CB, 2 * KST), blk, 0, stream>>>(h_bf, Wb_hg, KST, EpGates<__bf16>{Zb, RH, lx, b_hg, h_bf});
        gemm_bt<<<g(CB, KST), blk, 0, stream>>>(RH, Wb_hl, KST, EpLin<1, __bf16>{Zb, lx, b_hl, h_bf, ss, sn, h_bf, dtp});
        gemm_bt<<<g(CB, 2 * KST), blk, 0, stream>>>(h_bf, Wb_hg, KST, EpGates<__bf16>{Zb, RH, lx, b_hg, h_bf});
        gemm_bt<<<g(CB, KST), blk, 0, stream>>>(RH, Wb_hl, KST, EpLin<2, __bf16>{Zb, lx, b_hl, h_bf, ss, sn, h_bf, dtp});
        gemm_bt<<<g(CB, 2 * KST), blk, 0, stream>>>(h_bf, Wb_hg, KST, EpGates<__bf16>{Zb, RH, lx, b_hg, h_bf});
        gemm_bt<<<g(CB, KST), blk, 0, stream>>>(RH, Wb_hl, KST, EpLin<3, __bf16>{Zb, lx, b_hl, h_bf, ss, sn, snbs, dtp});
    }

    // y = tanh(state_new W_y1^T) W_y2^T ; t_bf reuses lx+Zb region
    const int CBY = (4 * CB < Bsz) ? 4 * CB : Bsz;
    for (int c0 = 0; c0 < Bsz; c0 += CBY) {
        gemm_bt<<<g(CBY, KST), blk, 0, stream>>>(snb + (size_t)c0 * KST, Wb_y1, KST, EpT{t_bf});
        gemm_bt<<<g(CBY, KOUT), blk, 0, stream>>>(t_bf, Wb_y2, KST, EpY{y_out + (size_t)c0 * KOUT});
    }
}

// Round 10
// 1336.542 us; speedup vs baseline: 1.8362x; 1.1517x over previous
//
#include <hip/hip_runtime.h>
#include <cstdint>
#include <cstddef>

#define DEVI __device__ __forceinline__

namespace {

constexpr int Bsz  = 16384;
constexpr int KIN  = 256;
constexpr int KST  = 1024;
constexpr int KOUT = 256;

typedef __bf16 bf16x8 __attribute__((ext_vector_type(8)));
typedef float  f32x4  __attribute__((ext_vector_type(4)));

DEVI float sigmoidf_(float x) { return 1.0f / (1.0f + expf(-x)); }

DEVI void gload16(const void* gsrc, void* ldst) {
    // async global->LDS, 16B/lane; per-wave dest = uniform base + lane*16
    __builtin_amdgcn_global_load_lds((__attribute__((address_space(1))) void*)gsrc,
                                     (__attribute__((address_space(3))) void*)ldst,
                                     16, 0, 0);
}

// ---- vectorized 8-element load/store helpers (16B-aligned by layout) ----
DEVI void ld8f(const float* p, float* v) {
    const float4 a = *(const float4*)p;
    const float4 b = *(const float4*)(p + 4);
    v[0]=a.x; v[1]=a.y; v[2]=a.z; v[3]=a.w;
    v[4]=b.x; v[5]=b.y; v[6]=b.z; v[7]=b.w;
}
DEVI void st8f(float* p, const float* v) {
    *(float4*)p       = (float4){v[0],v[1],v[2],v[3]};
    *(float4*)(p + 4) = (float4){v[4],v[5],v[6],v[7]};
}
DEVI void ld8bf(const __bf16* p, float* v) {
    const bf16x8 o = *(const bf16x8*)p;
#pragma unroll
    for (int i = 0; i < 8; ++i) v[i] = (float)o[i];
}
DEVI void st8bf(__bf16* p, const float* v) {
    bf16x8 o;
#pragma unroll
    for (int i = 0; i < 8; ++i) o[i] = (__bf16)v[i];
    *(bf16x8*)p = o;
}
DEVI void ld8h(const float* p, float* v)  { ld8f(p, v); }
DEVI void ld8h(const __bf16* p, float* v) { ld8bf(p, v); }

// ---------------- epilogues: store16(v[16], row, col0), col0 % 16 == 0 ----------------
struct EpX0 {
    __bf16* out; const float* bias;
    DEVI void begin() {}
    DEVI void store16(const float* v, int r, int c) {
#pragma unroll
        for (int q = 0; q < 2; ++q) {
            float b[8], o[8];
            ld8f(bias + c + q * 8, b);
#pragma unroll
            for (int e = 0; e < 8; ++e) o[e] = tanhf(v[q*8+e] + b[e]);
            st8bf(out + (size_t)r * KST + c + q * 8, o);
        }
    }
};
struct EpLx {
    __bf16* out;
    DEVI void begin() {}
    DEVI void store16(const float* v, int r, int c) {
#pragma unroll
        for (int q = 0; q < 2; ++q)
            st8bf(out + (size_t)r * (3 * KST) + c + q * 8, v + q * 8);
    }
};
template <class HT>
struct EpGates {
    __bf16* Z; __bf16* RH; const __bf16* lx; const float* bhg; const HT* h;
    DEVI void begin() {}
    DEVI void store16(const float* v, int r, int c) {
#pragma unroll
        for (int q = 0; q < 2; ++q) {
            float l[8], b[8], g[8];
            ld8bf(lx + (size_t)r * (3 * KST) + c + q * 8, l);
            ld8f(bhg + c + q * 8, b);
#pragma unroll
            for (int e = 0; e < 8; ++e) g[e] = sigmoidf_(l[e] + v[q*8+e] + b[e]);
            if (c < KST) {          // 1024 % 16 == 0: a 16-chunk never straddles
                st8bf(Z + (size_t)r * KST + c + q * 8, g);
            } else {
                const size_t i = (size_t)r * KST + (c - KST) + q * 8;
                float hh[8];
                ld8h(h + i, hh);
#pragma unroll
                for (int e = 0; e < 8; ++e) g[e] *= hh[e];
                st8bf(RH + i, g);
            }
        }
    }
};
template <int STAGE, class HT>
struct EpLin {
    const __bf16* Z; const __bf16* lx; const float* bhl; const HT* h;
    const float* state; float* acc; __bf16* hn; const float* dtp;
    float dtv;
    DEVI void begin() { dtv = *dtp; }
    DEVI void store16(const float* v, int r, int c) {
#pragma unroll
        for (int q = 0; q < 2; ++q) {
            const size_t i = (size_t)r * KST + c + q * 8;
            float l[8], z[8], hh[8], st[8], b[8], kk[8], ov[8], hv[8];
            ld8bf(lx + (size_t)r * (3 * KST) + 2 * KST + c + q * 8, l);
            ld8bf(Z + i, z);
            ld8h(h + i, hh);
            ld8f(state + i, st);
            ld8f(bhl + c + q * 8, b);
#pragma unroll
            for (int e = 0; e < 8; ++e)
                kk[e] = z[e] * (tanhf(l[e] + v[q*8+e] + b[e]) - hh[e]);
            if constexpr (STAGE == 0) {
#pragma unroll
                for (int e = 0; e < 8; ++e) { ov[e] = kk[e]; hv[e] = st[e] + 0.5f * dtv * kk[e]; }
            } else if constexpr (STAGE == 1 || STAGE == 2) {
                float a[8]; ld8f(acc + i, a);
                const float hc = (STAGE == 1) ? 0.5f : 1.0f;
#pragma unroll
                for (int e = 0; e < 8; ++e) { ov[e] = a[e] + 2.f * kk[e]; hv[e] = st[e] + hc * dtv * kk[e]; }
            } else {
                float a[8]; ld8f(acc + i, a);
#pragma unroll
                for (int e = 0; e < 8; ++e) { ov[e] = st[e] + dtv * (a[e] + kk[e]) * (1.f / 6.f); hv[e] = ov[e]; }
            }
            st8f(acc + i, ov);
            st8bf(hn + i, hv);
        }
    }
};
struct EpT {
    __bf16* out;
    DEVI void begin() {}
    DEVI void store16(const float* v, int r, int c) {
#pragma unroll
        for (int q = 0; q < 2; ++q) {
            float o[8];
#pragma unroll
            for (int e = 0; e < 8; ++e) o[e] = tanhf(v[q*8+e]);
            st8bf(out + (size_t)r * KST + c + q * 8, o);
        }
    }
};
struct EpY {
    float* out;
    DEVI void begin() {}
    DEVI void store16(const float* v, int r, int c) {
        st8f(out + (size_t)r * KOUT + c, v);
        st8f(out + (size_t)r * KOUT + c + 8, v + 8);
    }
};

// ---- shared MFMA micro-kernel for the 256x256 tile: one K-tile (BK=64) ----
DEVI void compute_tile64(const __bf16* a, const __bf16* b,
                         f32x4 (&acc)[8][4], int wr, int wc, int fr, int fq)
{
#pragma unroll
    for (int kk = 0; kk < 2; ++kk) {
        bf16x8 av[8], bv[4];
#pragma unroll
        for (int mi = 0; mi < 8; ++mi)
            av[mi] = *(const bf16x8*)&a[(wr * 128 + mi * 16 + fr) * 64 + kk * 32 + fq * 8];
#pragma unroll
        for (int ni = 0; ni < 4; ++ni)
            bv[ni] = *(const bf16x8*)&b[(wc * 64 + ni * 16 + fr) * 64 + kk * 32 + fq * 8];
#pragma unroll
        for (int mi = 0; mi < 8; ++mi)
#pragma unroll
            for (int ni = 0; ni < 4; ++ni)
                acc[mi][ni] = __builtin_amdgcn_mfma_f32_16x16x32_bf16(av[mi], bv[ni], acc[mi][ni], 0, 0, 0);
    }
}

// ---------------- 256x256 bf16 MFMA GEMM, T3-minimum 2-phase prefetch ----------------
// C[M,N] = A[M,K] @ W[N,K]^T. 512 thr (8 waves, 2Mx4N; 128x64/wave), BK=64,
// double-buffered 128KB LDS, global_load_lds w16, linear LDS (no swizzle: T2 null
// at 2ph), STAGE(t+1) issued BEFORE COMPUTE(t), ONE vmcnt(0)+barrier per K-tile.
// Epilogue: LDS-bounce (8 bands x 32 rows, stride 258 -> 2-way write = free).
template <class Ep>
__global__ __launch_bounds__(512, 2)
void gemm_bt2(const __bf16* __restrict__ A, const __bf16* __restrict__ W,
              const int K, Ep ep)
{
    __shared__ __bf16 sm[4][256 * 64];   // [buf*2 + (0=A,1=B)] -> 128 KiB
    const int m0 = blockIdx.x * 256;
    const int n0 = blockIdx.y * 256;
    const int t  = threadIdx.x;
    const int l  = t & 63;
    const int w  = t >> 6;           // 0..7
    const int wr = w >> 2;           // 0..1 -> 128-row half
    const int wc = w & 3;            // 0..3 -> 64-col quarter
    const int fr = l & 15;
    const int fq = l >> 4;
    const int srow = t >> 3;         // staging row 0..63 (per 64-row group)
    const int scol = (t & 7) << 3;   // staging k elem 0..56

    const __bf16* Ap = A + (size_t)(m0 + srow) * K + scol;
    const __bf16* Bp = W + (size_t)(n0 + srow) * K + scol;

    f32x4 acc[8][4];
#pragma unroll
    for (int i = 0; i < 8; ++i)
#pragma unroll
        for (int j = 0; j < 4; ++j) acc[i][j] = (f32x4){0.f, 0.f, 0.f, 0.f};

    const int NT = K >> 6;

#define STAGE_KT(buf, kt)                                                     \
    {                                                                         \
        const int k0_ = (kt) << 6;                                            \
        __bf16* da_ = &sm[(buf) * 2 + 0][t * 8];                              \
        __bf16* db_ = &sm[(buf) * 2 + 1][t * 8];                              \
        _Pragma("unroll")                                                     \
        for (int q = 0; q < 4; ++q) {                                         \
            gload16(Ap + (size_t)(q * 64) * K + k0_, da_ + q * 4096);         \
            gload16(Bp + (size_t)(q * 64) * K + k0_, db_ + q * 4096);         \
        }                                                                     \
    }

    STAGE_KT(0, 0);
    __syncthreads();                 // drain vmcnt(0): tile 0 resident
    int cur = 0;
    for (int kt = 0; kt < NT - 1; ++kt) {
        STAGE_KT(cur ^ 1, kt + 1);   // next tile in flight DURING compute
        compute_tile64(sm[cur * 2 + 0], sm[cur * 2 + 1], acc, wr, wc, fr, fq);
        __syncthreads();             // one vmcnt(0)+lgkmcnt(0)+barrier per tile
        cur ^= 1;
    }
    compute_tile64(sm[cur * 2 + 0], sm[cur * 2 + 1], acc, wr, wc, fr, fq);
    __syncthreads();                 // all LDS reads done before bounce reuse
#undef STAGE_KT

    // ---- LDS-bounce epilogue: band b = rows 32b..32b+31; owner wr = b>>2,
    // mi in {2(b&3), 2(b&3)+1}. stride 258 -> write banks exactly 2-way (free).
    float* bounce = (float*)&sm[0][0];           // 32*258*4 = 33 KB
    ep.begin();
#pragma unroll
    for (int band = 0; band < 8; ++band) {
        if (wr == (band >> 2)) {
            const int mi0 = 2 * (band & 3);
#pragma unroll
            for (int mm = 0; mm < 2; ++mm)
#pragma unroll
                for (int ni = 0; ni < 4; ++ni)
#pragma unroll
                    for (int j = 0; j < 4; ++j)
                        bounce[(mm * 16 + fq * 4 + j) * 258 + wc * 64 + ni * 16 + fr]
                            = acc[mi0 + mm][ni][j];
        }
        __syncthreads();
        {
            const int r  = t >> 4;               // 0..31
            const int c0 = (t & 15) * 16;        // 0..240
            float v[16];
#pragma unroll
            for (int k2 = 0; k2 < 16; ++k2) v[k2] = bounce[r * 258 + c0 + k2];
            ep.store16(v, m0 + band * 32 + r, n0 + c0);
        }
        __syncthreads();
    }
}

// ---------------- 128x128 kernel (R9-verified) retained for y2 (N=256) ----------------
template <class Ep>
__global__ __launch_bounds__(256)
void gemm_bt(const __bf16* __restrict__ A, const __bf16* __restrict__ W,
             const int K, Ep ep)
{
    __shared__ __bf16 As[128 * 32];
    __shared__ __bf16 Bs[128 * 32];
    __shared__ float  bounce[32 * 132];
    const int m0 = blockIdx.x * 128;
    const int n0 = blockIdx.y * 128;
    const int t  = threadIdx.x;
    const int l  = t & 63;
    const int w  = t >> 6;
    const int wr = w >> 1;
    const int wc = w & 1;
    const int fr = l & 15;
    const int fq = l >> 4;
    const int srow = t >> 2;
    const int sk   = (t & 3) << 3;

    const __bf16* Ap0 = A + (size_t)(m0 + srow) * K + sk;
    const __bf16* Ap1 = Ap0 + (size_t)64 * K;
    const __bf16* Bp0 = W + (size_t)(n0 + srow) * K + sk;
    const __bf16* Bp1 = Bp0 + (size_t)64 * K;
    __bf16* la0 = &As[t * 8];
    __bf16* la1 = &As[2048 + t * 8];
    __bf16* lb0 = &Bs[t * 8];
    __bf16* lb1 = &Bs[2048 + t * 8];

    f32x4 acc[4][4];
#pragma unroll
    for (int i = 0; i < 4; ++i)
#pragma unroll
        for (int j = 0; j < 4; ++j) acc[i][j] = (f32x4){0.f, 0.f, 0.f, 0.f};

    for (int k0 = 0; k0 < K; k0 += 32) {
        gload16(Ap0 + k0, la0);
        gload16(Ap1 + k0, la1);
        gload16(Bp0 + k0, lb0);
        gload16(Bp1 + k0, lb1);
        __syncthreads();
        bf16x8 av[4], bv[4];
#pragma unroll
        for (int mi = 0; mi < 4; ++mi)
            av[mi] = *(const bf16x8*)&As[(wr * 64 + mi * 16 + fr) * 32 + fq * 8];
#pragma unroll
        for (int ni = 0; ni < 4; ++ni)
            bv[ni] = *(const bf16x8*)&Bs[(wc * 64 + ni * 16 + fr) * 32 + fq * 8];
#pragma unroll
        for (int mi = 0; mi < 4; ++mi)
#pragma unroll
            for (int ni = 0; ni < 4; ++ni)
                acc[mi][ni] = __builtin_amdgcn_mfma_f32_16x16x32_bf16(av[mi], bv[ni], acc[mi][ni], 0, 0, 0);
        __syncthreads();
    }

    ep.begin();
#pragma unroll
    for (int band = 0; band < 4; ++band) {
        if (wr == (band >> 1)) {
            const int mi0 = 2 * (band & 1);
#pragma unroll
            for (int mm = 0; mm < 2; ++mm)
#pragma unroll
                for (int ni = 0; ni < 4; ++ni)
#pragma unroll
                    for (int j = 0; j < 4; ++j)
                        bounce[(mm * 16 + fq * 4 + j) * 132 + wc * 64 + ni * 16 + fr]
                            = acc[mi0 + mm][ni][j];
        }
        __syncthreads();
        {
            const int r  = t >> 3;
            const int c0 = (t & 7) * 16;
            float v[16];
#pragma unroll
            for (int kk = 0; kk < 16; ++kk) v[kk] = bounce[r * 132 + c0 + kk];
            ep.store16(v, m0 + band * 32 + r, n0 + c0);
        }
        __syncthreads();
    }
}

// ---------------- f32 -> bf16 conversion ----------------
__global__ __launch_bounds__(256)
void cvt_bf16(const float* __restrict__ s, __bf16* __restrict__ d, int n8)
{
    for (int i = blockIdx.x * blockDim.x + threadIdx.x; i < n8; i += gridDim.x * blockDim.x) {
        const float4 a = ((const float4*)s)[2 * i];
        const float4 b = ((const float4*)s)[2 * i + 1];
        bf16x8 v;
        v[0] = (__bf16)a.x; v[1] = (__bf16)a.y; v[2] = (__bf16)a.z; v[3] = (__bf16)a.w;
        v[4] = (__bf16)b.x; v[5] = (__bf16)b.y; v[6] = (__bf16)b.z; v[7] = (__bf16)b.w;
        ((bf16x8*)d)[i] = v;
    }
}

} // namespace

extern "C" void kernel_launch(void* const* d_in, const int* in_sizes, int n_in,
                              void* d_out, int out_size, void* d_ws, size_t ws_size,
                              hipStream_t stream)
{
    (void)in_sizes; (void)n_in; (void)out_size;

    const float* x     = (const float*)d_in[0];
    const float* state = (const float*)d_in[1];
    const float* dtp   = (const float*)d_in[2];
    const float* W_in  = (const float*)d_in[3];
    const float* b_in  = (const float*)d_in[4];
    const float* W_lx  = (const float*)d_in[5];
    const float* W_hg  = (const float*)d_in[6];
    const float* b_hg  = (const float*)d_in[7];
    const float* W_hl  = (const float*)d_in[8];
    const float* b_hl  = (const float*)d_in[9];
    const float* W_y1  = (const float*)d_in[10];
    const float* W_y2  = (const float*)d_in[11];

    float* y_out  = (float*)d_out;
    float* st_new = y_out + (size_t)Bsz * KOUT;

    // fixed ~88 MB + chunk 12*CB*K bytes. CB=16384 total ~289 MB, CB=8192 ~188 MB.
    // (R8's CB=16384 regression was epilogue-scatter overfetch, fixed in R9 ->
    //  full-batch is safe and halves dispatch count / doubles grids.)
    const size_t nWin = (size_t)KST * KIN, nWlx = (size_t)3 * KST * KST,
                 nWhg = (size_t)2 * KST * KST, nWhl = (size_t)KST * KST,
                 nWy1 = (size_t)KST * KST, nWy2 = (size_t)KOUT * KST;
    const size_t fixedB = ((size_t)Bsz * KIN + 2 * (size_t)Bsz * KST
                           + nWin + nWlx + nWhg + nWhl + nWy1 + nWy2) * 2;

    int CB = 1024;
    while (CB < Bsz && fixedB + (size_t)(2 * CB) * KST * 12 <= ws_size) CB <<= 1;
    if (fixedB + (size_t)CB * KST * 12 > ws_size) return;

    uint8_t* p = (uint8_t*)d_ws;
    __bf16* x_bf  = (__bf16*)p; p += (size_t)Bsz * KIN * 2;
    __bf16* st_bf = (__bf16*)p; p += (size_t)Bsz * KST * 2;
    __bf16* snb   = (__bf16*)p; p += (size_t)Bsz * KST * 2;
    __bf16* Wb_in = (__bf16*)p; p += nWin * 2;
    __bf16* Wb_lx = (__bf16*)p; p += nWlx * 2;
    __bf16* Wb_hg = (__bf16*)p; p += nWhg * 2;
    __bf16* Wb_hl = (__bf16*)p; p += nWhl * 2;
    __bf16* Wb_y1 = (__bf16*)p; p += nWy1 * 2;
    __bf16* Wb_y2 = (__bf16*)p; p += nWy2 * 2;
    __bf16* lx    = (__bf16*)p; p += (size_t)CB * 3 * KST * 2;
    __bf16* Zb    = (__bf16*)p; p += (size_t)CB * KST * 2;
    __bf16* h_bf  = (__bf16*)p; p += (size_t)CB * KST * 2;
    __bf16* RH    = (__bf16*)p;
    __bf16* t_bf  = lx;     // y-phase scratch aliases lx+Zb (8*CB*K bytes)

    const dim3 blk(256), blk2(512);
    auto cg = [](size_t n) { return dim3((unsigned)((n / 8 + 255) / 256 > 2048 ? 2048 : (n / 8 + 255) / 256)); };
    auto g1 = [](int M, int N) { return dim3((unsigned)(M / 128), (unsigned)(N / 128)); };
    auto g2 = [](int M, int N) { return dim3((unsigned)(M / 256), (unsigned)(N / 256)); };

    cvt_bf16<<<cg((size_t)Bsz * KIN), blk, 0, stream>>>(x, x_bf, (int)((size_t)Bsz * KIN / 8));
    cvt_bf16<<<cg((size_t)Bsz * KST), blk, 0, stream>>>(state, st_bf, (int)((size_t)Bsz * KST / 8));
    cvt_bf16<<<cg(nWin), blk, 0, stream>>>(W_in, Wb_in, (int)(nWin / 8));
    cvt_bf16<<<cg(nWlx), blk, 0, stream>>>(W_lx, Wb_lx, (int)(nWlx / 8));
    cvt_bf16<<<cg(nWhg), blk, 0, stream>>>(W_hg, Wb_hg, (int)(nWhg / 8));
    cvt_bf16<<<cg(nWhl), blk, 0, stream>>>(W_hl, Wb_hl, (int)(nWhl / 8));
    cvt_bf16<<<cg(nWy1), blk, 0, stream>>>(W_y1, Wb_y1, (int)(nWy1 / 8));
    cvt_bf16<<<cg(nWy2), blk, 0, stream>>>(W_y2, Wb_y2, (int)(nWy2 / 8));

    for (int c0 = 0; c0 < Bsz; c0 += CB) {
        const __bf16* xs  = x_bf + (size_t)c0 * KIN;
        const __bf16* ssb = st_bf + (size_t)c0 * KST;
        const float*  ss  = state + (size_t)c0 * KST;
        float*  sn   = st_new + (size_t)c0 * KST;
        __bf16* snbs = snb + (size_t)c0 * KST;

        gemm_bt2<<<g2(CB, KST), blk2, 0, stream>>>(xs, Wb_in, KIN, EpX0{h_bf, b_in});
        gemm_bt2<<<g2(CB, 3 * KST), blk2, 0, stream>>>(h_bf, Wb_lx, KST, EpLx{lx});

        gemm_bt2<<<g2(CB, 2 * KST), blk2, 0, stream>>>(ssb, Wb_hg, KST, EpGates<float>{Zb, RH, lx, b_hg, ss});
        gemm_bt2<<<g2(CB, KST), blk2, 0, stream>>>(RH, Wb_hl, KST, EpLin<0, float>{Zb, lx, b_hl, ss, ss, sn, h_bf, dtp});
        gemm_bt2<<<g2(CB, 2 * KST), blk2, 0, stream>>>(h_bf, Wb_hg, KST, EpGates<__bf16>{Zb, RH, lx, b_hg, h_bf});
        gemm_bt2<<<g2(CB, KST), blk2, 0, stream>>>(RH, Wb_hl, KST, EpLin<1, __bf16>{Zb, lx, b_hl, h_bf, ss, sn, h_bf, dtp});
        gemm_bt2<<<g2(CB, 2 * KST), blk2, 0, stream>>>(h_bf, Wb_hg, KST, EpGates<__bf16>{Zb, RH, lx, b_hg, h_bf});
        gemm_bt2<<<g2(CB, KST), blk2, 0, stream>>>(RH, Wb_hl, KST, EpLin<2, __bf16>{Zb, lx, b_hl, h_bf, ss, sn, h_bf, dtp});
        gemm_bt2<<<g2(CB, 2 * KST), blk2, 0, stream>>>(h_bf, Wb_hg, KST, EpGates<__bf16>{Zb, RH, lx, b_hg, h_bf});
        gemm_bt2<<<g2(CB, KST), blk2, 0, stream>>>(RH, Wb_hl, KST, EpLin<3, __bf16>{Zb, lx, b_hl, h_bf, ss, sn, snbs, dtp});
    }

    // y = tanh(state_new W_y1^T) W_y2^T ; y2 keeps the 128^2 kernel (N=256 grid)
    const int CBY = (4 * CB < Bsz) ? 4 * CB : Bsz;
    for (int c0 = 0; c0 < Bsz; c0 += CBY) {
        gemm_bt2<<<g2(CBY, KST), blk2, 0, stream>>>(snb + (size_t)c0 * KST, Wb_y1, KST, EpT{t_bf});
        gemm_bt<<<g1(CBY, KOUT), blk, 0, stream>>>(t_bf, Wb_y2, KST, EpY{y_out + (size_t)c0 * KOUT});
    }
}